// Round 19
// baseline (267.171 us; speedup 1.0000x reference)
//
#include <hip/hip_runtime.h>

// VQ-VAE quantization: z [16384 x 512] f32, codebook [8192 x 512] f32.
// out = concat(z_st [16384*512] f32, vq_loss [1] f32).
//
// R4: MX-fp8 (e4m3, K=128 scaled MFMA) GEMM; packed (dist|idx) u32 argmin.
// R17: atomicMin candidate reduce, streaming gather.
// R21 (119.9µs gemm): single-buffer 32KB, (256,2), 4 blocks/CU (VGPR-capped
// 16 waves), conflict-free o0/o1 frag reads, es in regs.
// R22 (this): A-tile bypasses LDS. Pipe audit: LDS 45% = fattest; A frags
// are contiguous 32B/lane from global (wave = 16 full 128B lines, L2-hot
// via XCD remap; 2x read amplification absorbed by L2 headroom). LDS now
// stages only B (16KB): stage-writes halved, A LDS reads gone -> LDS
// ~8k cyc/round. A natural K-order + B o0/o1 exact K-order = operands
// match. Reg budget: acc 64 + A 32 + 1 B frag 8 + misc ~116 < 128 cap.

#define M_ROWS 16384
#define K_CODES 8192
#define DIM 512
#define BM 128
#define BN 128
#define BK 128                 // fp8 bytes per K-step (one 16x16x128 MFMA)
#define NT (K_CODES / BN)      // 64 ktiles
#define OUT0_SIZE (M_ROWS * DIM)
#define GB_BLOCKS 1024

typedef int   i32x8 __attribute__((ext_vector_type(8)));
typedef float f32x4 __attribute__((ext_vector_type(4)));

template <bool HI>
__device__ __forceinline__ int pk8(float a, float b, int old) {
    return __builtin_amdgcn_cvt_pk_fp8_f32(a, b, old, HI);
}

__device__ __forceinline__ void gload_lds(const unsigned char* g, unsigned char* l) {
    __builtin_amdgcn_global_load_lds((const __attribute__((address_space(1))) void*)g,
                                     (__attribute__((address_space(3))) void*)l, 16, 0, 0);
}

// ---- kernel 1: fused converts + candMin init ---------------------------
__global__ __launch_bounds__(256) void convert_all(
    const float* __restrict__ z, const float* __restrict__ cb,
    unsigned char* __restrict__ z8, unsigned char* __restrict__ cb8,
    float* __restrict__ enorm, unsigned int* __restrict__ candMin,
    float* __restrict__ lossSlot)
{
    const int tid = threadIdx.x;
    if (blockIdx.x == 0 && tid == 0) *lossSlot = 0.f;   // gather accumulates
    {   // blocks 0..63 init candMin[16384]
        int gi = blockIdx.x * 256 + tid;
        if (gi < M_ROWS) candMin[gi] = 0xFFFFFFFFu;
    }
    if (blockIdx.x < K_CODES / 4) {
        const int w = tid >> 6, lane = tid & 63;
        const int row = blockIdx.x * 4 + w;
        const float* src = cb + (size_t)row * DIM + lane * 8;
        float4 a = *(const float4*)(src);
        float4 b = *(const float4*)(src + 4);
        float ns = a.x * a.x + a.y * a.y + a.z * a.z + a.w * a.w
                 + b.x * b.x + b.y * b.y + b.z * b.z + b.w * b.w;
        const float S = 8192.0f;                 // exact power of 2
        int lo = 0, hi = 0;
        lo = pk8<false>(a.x * S, a.y * S, lo); lo = pk8<true>(a.z * S, a.w * S, lo);
        hi = pk8<false>(b.x * S, b.y * S, hi); hi = pk8<true>(b.z * S, b.w * S, hi);
        *(int2*)(cb8 + (size_t)row * DIM + lane * 8) = make_int2(lo, hi);
        for (int m = 32; m; m >>= 1) ns += __shfl_down(ns, m, 64);
        if (lane == 0) enorm[row] = S * ns;      // 8192 * ||e||^2 (f32-exact norm)
    } else {
        size_t i = ((size_t)(blockIdx.x - K_CODES / 4) * 256 + tid) * 8;
        float4 a = *(const float4*)(z + i);
        float4 b = *(const float4*)(z + i + 4);
        int lo = 0, hi = 0;
        lo = pk8<false>(a.x, a.y, lo); lo = pk8<true>(a.z, a.w, lo);
        hi = pk8<false>(b.x, b.y, hi); hi = pk8<true>(b.z, b.w, hi);
        *(int2*)(z8 + i) = make_int2(lo, hi);
    }
}

// ---- kernel 2: MX-fp8 GEMM (128x128, 4 waves) — A direct, B in LDS -----
__global__ __launch_bounds__(256, 2) void gemm_argmin(
    const unsigned char* __restrict__ z8, const unsigned char* __restrict__ cbb,
    const float* __restrict__ enorm, unsigned int* __restrict__ candMin)
{
    __shared__ alignas(32) unsigned char Bs[BN * BK];   // 16 KB (B only)

    const int tid = threadIdx.x;
    const int lane = tid & 63;
    const int w = tid >> 6;             // 0..3
    // XCD remap: b&7 = XCD; XCD owns mtiles [xcd*16,xcd*16+16) (1MB A
    // slice, L2-hot); ktile advances every 128 blocks.
    const int b = blockIdx.x;
    const int xcd = b & 7;
    const int idx = b >> 3;             // 0..1023
    const int ktile = idx >> 4;         // 0..63
    const int mtile = xcd * 16 + (idx & 15);
    const int mbase = mtile * BM;
    const int nbase = ktile * BN;

    const int rA = lane >> 3;           // row within 8-row chunk
    const int jG = ((lane & 7) ^ rA) * 16;  // pre-swizzled global 16B chunk (B)
    const int quad = lane >> 4;
    const int l15 = lane & 15;
    const int sw = l15 & 7;
    const int rw = (w >> 1) * 64;       // wave row quadrant
    const int cw = (w & 1) * 64;        // wave col quadrant
    // B read: LDS slot s of row r holds global chunk s^(r&7); lane needs
    // chunks 2q,2q+1 -> slots o0=((2q)^sw)*16, o1=o0^16 (exact K order,
    // conflict-free: 8 distinct 16B cols per 16 lanes).
    const int o0 = ((quad << 1) ^ sw) * 16;
    const int o1 = o0 ^ 16;

    // epilogue norms straight to regs (64B-coalesced per quad, L2-hot)
    float es[4];
#pragma unroll
    for (int cf = 0; cf < 4; ++cf) es[cf] = enorm[nbase + cw + cf * 16 + l15];

    f32x4 acc[16];
#pragma unroll
    for (int i = 0; i < 16; ++i) acc[i] = (f32x4){0.f, 0.f, 0.f, 0.f};

#pragma unroll 1
    for (int dt = 0; dt < 4; ++dt) {
        // A fragments: direct global->reg, natural K order. Wave reads 16
        // full 128B lines (rows rw..rw+63 x 128B at dt*128), L2-hot.
        i32x8 af[4];
#pragma unroll
        for (int rf = 0; rf < 4; ++rf)
            af[rf] = *(const i32x8*)(z8 + (size_t)(mbase + rw + rf * 16 + l15) * DIM
                                        + dt * BK + quad * 32);
        // stage B tile (4 gload_lds / thread, chunks w*4+i)
#pragma unroll
        for (int i_ = 0; i_ < 4; ++i_) {
            int c_ = w * 4 + i_;        // 1KB chunk id (0..15): rows c*8..c*8+7
            int row_ = c_ * 8 + rA;
            gload_lds(cbb + (size_t)(nbase + row_) * DIM + dt * BK + jG,
                      Bs + c_ * 1024 + lane * 16);
        }
        __syncthreads();   // vmcnt(0) drain: af in regs, Bs in LDS
        // cf-outer, 1 live B frag; inner loop pure MFMA (A already in regs)
#pragma unroll
        for (int cf = 0; cf < 4; ++cf) {
            const unsigned char* pb = Bs + (cw + cf * 16 + l15) * BK;
            int4 lo = *(const int4*)(pb + o0);
            int4 hi = *(const int4*)(pb + o1);
            i32x8 bf = (i32x8){lo.x, lo.y, lo.z, lo.w, hi.x, hi.y, hi.z, hi.w};
#pragma unroll
            for (int rf = 0; rf < 4; ++rf)
                acc[rf * 4 + cf] = __builtin_amdgcn_mfma_scale_f32_16x16x128_f8f6f4(
                    af[rf], bf, acc[rf * 4 + cf],
                    0, 0, 0, 0x7F7F7F7F, 0, 0x7F7F7F7F);
        }
        __syncthreads();   // B reads done before next stage overwrites
    }

    // epilogue: per-row argmin over this tile's 128 cols -> atomicMin.
    // C/D layout: col = lane&15, row = quad*4 + reg.
    // Packed key: monotone-uint(dist), low 13 bits = global code index.
#pragma unroll
    for (int rf = 0; rf < 4; ++rf) {
#pragma unroll
        for (int r = 0; r < 4; ++r) {
            float bv = 3.4e38f; int bi = 0;
#pragma unroll
            for (int cf = 0; cf < 4; ++cf) {
                int col = cw + cf * 16 + l15;
                float dist = fmaf(-2.0f, acc[rf * 4 + cf][r], es[cf]);
                if (dist < bv) { bv = dist; bi = col; }  // strict <: low col on tie
            }
            unsigned u = __builtin_bit_cast(unsigned, bv);
            u ^= ((unsigned)(((int)u) >> 31)) | 0x80000000u;
            unsigned key = (u & 0xFFFFE000u) | (unsigned)(nbase + bi);
#pragma unroll
            for (int m = 1; m < 16; m <<= 1) {
                unsigned o = __shfl_xor(key, m, 64);
                key = o < key ? o : key;
            }
            if (l15 == 0)
                atomicMin(&candMin[mbase + rw + rf * 16 + quad * 4 + r], key);
        }
    }
}

// ---- kernel 3: gather + ST output + loss atomic ------------------------
// Pure streaming: per row one uniform key read, then 128 float4 slots.
// One plain atomicAdd per block for the loss.
__global__ __launch_bounds__(256) void gather_out(
    const float* __restrict__ z, const float* __restrict__ cb,
    const unsigned int* __restrict__ candMin, float* __restrict__ out)
{
    __shared__ float red[4];
    const int tid = threadIdx.x;
    const int w = tid >> 6, lane = tid & 63;
    float lsum = 0.f;
#pragma unroll
    for (int it = 0; it < M_ROWS / (GB_BLOCKS * 4); ++it) {
        int row = (it * GB_BLOCKS + blockIdx.x) * 4 + w;
        int k = (int)(candMin[row] & 8191u);    // uniform per wave
#pragma unroll
        for (int j = 0; j < 2; ++j) {
            int slot = lane + j * 64;
            float4 zv = ((const float4*)(z + (size_t)row * DIM))[slot];
            float4 cv = ((const float4*)(cb + (size_t)k * DIM))[slot];
            float dx = cv.x - zv.x, dy = cv.y - zv.y;
            float dz2 = cv.z - zv.z, dw = cv.w - zv.w;
            float4 o = {zv.x + dx, zv.y + dy, zv.z + dz2, zv.w + dw};  // z + sg(zq-z)
            ((float4*)(out + (size_t)row * DIM))[slot] = o;
            lsum += dx * dx + dy * dy + dz2 * dz2 + dw * dw;
        }
    }
    for (int m = 32; m; m >>= 1) lsum += __shfl_down(lsum, m, 64);
    if (lane == 0) red[w] = lsum;
    __syncthreads();
    if (tid == 0) {
        float t = (red[0] + red[1]) + (red[2] + red[3]);
        atomicAdd(out + OUT0_SIZE, t * (1.1f / (float)OUT0_SIZE));  // vq_loss = 1.1*mean
    }
}

extern "C" void kernel_launch(void* const* d_in, const int* in_sizes, int n_in,
                              void* d_out, int out_size, void* d_ws, size_t ws_size,
                              hipStream_t stream) {
    const float* z = (const float*)d_in[0];     // 16*1024*512
    const float* cb = (const float*)d_in[1];    // 8192*512
    float* out = (float*)d_out;                 // 8388608 + 1
    char* ws = (char*)d_ws;

    // ws layout (bytes)
    unsigned char* z8     = (unsigned char*)(ws);             //  8,388,608
    unsigned char* cb8    = (unsigned char*)(ws + 8388608);   //  4,194,304
    float* enorm          = (float*)(ws + 12582912);          //     32,768
    unsigned int* candMin = (unsigned int*)(ws + 12615680);   //     65,536

    convert_all<<<K_CODES / 4 + M_ROWS * DIM / 2048, 256, 0, stream>>>(
        z, cb, z8, cb8, enorm, candMin, out + OUT0_SIZE);
    gemm_argmin<<<NT * (M_ROWS / BM), 256, 0, stream>>>(z8, cb8, enorm, candMin);
    gather_out<<<GB_BLOCKS, 256, 0, stream>>>(z, cb, candMin, out);
}

// Round 20
// 232.516 us; speedup vs baseline: 1.1490x; 1.1490x over previous
//
#include <hip/hip_runtime.h>

// VQ-VAE quantization: z [16384 x 512] f32, codebook [8192 x 512] f32.
// out = concat(z_st [16384*512] f32, vq_loss [1] f32).
//
// R4: MX-fp8 (e4m3, K=128 scaled MFMA) GEMM; packed (dist|idx) u32 argmin.
// R17: atomicMin candidate reduce, streaming gather.
// R21 (119.9µs gemm, BEST): single-buffer 32KB, (256,2), conflict-free
// o0/o1 frag reads (full sw), es in regs, minimal 8 frag reads/wave-dt.
// R22 (A-direct): REGRESSED 120->166 (scattered 32B VMEM + exposed L2
// latency beat by LDS staging). REVERTED.
// R23 (this): R21 gemm byte-for-byte; gather_out at 2048 blocks (2 iters)
// to shorten the streaming tail. All gemm structural variants tested
// (deep-block/persistent/counted-vmcnt/512thr/A-direct) lost; this is
// the converged structure.

#define M_ROWS 16384
#define K_CODES 8192
#define DIM 512
#define BM 128
#define BN 128
#define BK 128                 // fp8 bytes per K-step (one 16x16x128 MFMA)
#define NT (K_CODES / BN)      // 64 ktiles
#define OUT0_SIZE (M_ROWS * DIM)
#define GB_BLOCKS 2048

typedef int   i32x8 __attribute__((ext_vector_type(8)));
typedef float f32x4 __attribute__((ext_vector_type(4)));

template <bool HI>
__device__ __forceinline__ int pk8(float a, float b, int old) {
    return __builtin_amdgcn_cvt_pk_fp8_f32(a, b, old, HI);
}

__device__ __forceinline__ void gload_lds(const unsigned char* g, unsigned char* l) {
    __builtin_amdgcn_global_load_lds((const __attribute__((address_space(1))) void*)g,
                                     (__attribute__((address_space(3))) void*)l, 16, 0, 0);
}

// ---- kernel 1: fused converts + candMin init ---------------------------
__global__ __launch_bounds__(256) void convert_all(
    const float* __restrict__ z, const float* __restrict__ cb,
    unsigned char* __restrict__ z8, unsigned char* __restrict__ cb8,
    float* __restrict__ enorm, unsigned int* __restrict__ candMin,
    float* __restrict__ lossSlot)
{
    const int tid = threadIdx.x;
    if (blockIdx.x == 0 && tid == 0) *lossSlot = 0.f;   // gather accumulates
    {   // blocks 0..63 init candMin[16384]
        int gi = blockIdx.x * 256 + tid;
        if (gi < M_ROWS) candMin[gi] = 0xFFFFFFFFu;
    }
    if (blockIdx.x < K_CODES / 4) {
        const int w = tid >> 6, lane = tid & 63;
        const int row = blockIdx.x * 4 + w;
        const float* src = cb + (size_t)row * DIM + lane * 8;
        float4 a = *(const float4*)(src);
        float4 b = *(const float4*)(src + 4);
        float ns = a.x * a.x + a.y * a.y + a.z * a.z + a.w * a.w
                 + b.x * b.x + b.y * b.y + b.z * b.z + b.w * b.w;
        const float S = 8192.0f;                 // exact power of 2
        int lo = 0, hi = 0;
        lo = pk8<false>(a.x * S, a.y * S, lo); lo = pk8<true>(a.z * S, a.w * S, lo);
        hi = pk8<false>(b.x * S, b.y * S, hi); hi = pk8<true>(b.z * S, b.w * S, hi);
        *(int2*)(cb8 + (size_t)row * DIM + lane * 8) = make_int2(lo, hi);
        for (int m = 32; m; m >>= 1) ns += __shfl_down(ns, m, 64);
        if (lane == 0) enorm[row] = S * ns;      // 8192 * ||e||^2 (f32-exact norm)
    } else {
        size_t i = ((size_t)(blockIdx.x - K_CODES / 4) * 256 + tid) * 8;
        float4 a = *(const float4*)(z + i);
        float4 b = *(const float4*)(z + i + 4);
        int lo = 0, hi = 0;
        lo = pk8<false>(a.x, a.y, lo); lo = pk8<true>(a.z, a.w, lo);
        hi = pk8<false>(b.x, b.y, hi); hi = pk8<true>(b.z, b.w, hi);
        *(int2*)(z8 + i) = make_int2(lo, hi);
    }
}

// ---- kernel 2: MX-fp8 GEMM (128x128, 4 waves, 4 blocks/CU) + atomicMin -
__global__ __launch_bounds__(256, 2) void gemm_argmin(
    const unsigned char* __restrict__ z8, const unsigned char* __restrict__ cbb,
    const float* __restrict__ enorm, unsigned int* __restrict__ candMin)
{
    __shared__ alignas(32) unsigned char As[BM * BK];   // 16 KB single buffer
    __shared__ alignas(32) unsigned char Bs[BN * BK];   // 16 KB single buffer
    // no Es: LDS = 32768 B exactly

    const int tid = threadIdx.x;
    const int lane = tid & 63;
    const int w = tid >> 6;             // 0..3
    // XCD remap: b&7 = XCD; XCD owns mtiles [xcd*16,xcd*16+16) (1MB A
    // slice, L2-hot); ktile advances every 128 blocks.
    const int b = blockIdx.x;
    const int xcd = b & 7;
    const int idx = b >> 3;             // 0..1023
    const int ktile = idx >> 4;         // 0..63
    const int mtile = xcd * 16 + (idx & 15);
    const int mbase = mtile * BM;
    const int nbase = ktile * BN;

    const int rA = lane >> 3;           // row within 8-row chunk
    const int jG = ((lane & 7) ^ rA) * 16;  // pre-swizzled global 16B chunk
    const int quad = lane >> 4;
    const int l15 = lane & 15;
    const int sw = l15 & 7;
    const int rw = (w >> 1) * 64;       // wave row quadrant
    const int cw = (w & 1) * 64;        // wave col quadrant
    // LDS slot s of row r holds global chunk s^(r&7). Lane needs global
    // chunks 2q,2q+1 -> slots o0=((2q)^sw)*16, o1=o0^16 (lo/hi in exact K
    // order). Full sw: 8 distinct 16B cols per 16 lanes -> bank 4c mod 32,
    // 2 lanes/col = conflict-free.
    const int o0 = ((quad << 1) ^ sw) * 16;
    const int o1 = o0 ^ 16;

    // epilogue norms straight to regs (64B-coalesced per quad, L2-hot)
    float es[4];
#pragma unroll
    for (int cf = 0; cf < 4; ++cf) es[cf] = enorm[nbase + cw + cf * 16 + l15];

    f32x4 acc[16];
#pragma unroll
    for (int i = 0; i < 16; ++i) acc[i] = (f32x4){0.f, 0.f, 0.f, 0.f};

#pragma unroll 1
    for (int dt = 0; dt < 4; ++dt) {
        // stage this K-slab (8 gload_lds / thread)
#pragma unroll
        for (int i_ = 0; i_ < 4; ++i_) {
            int c_ = w * 4 + i_;        // 1KB chunk id (0..15): rows c*8..c*8+7
            int row_ = c_ * 8 + rA;
            int col_ = dt * BK + jG;
            gload_lds(z8 + (size_t)(mbase + row_) * DIM + col_,
                      As + c_ * 1024 + lane * 16);
            gload_lds(cbb + (size_t)(nbase + row_) * DIM + col_,
                      Bs + c_ * 1024 + lane * 16);
        }
        __syncthreads();   // vmcnt(0) drain; other co-resident blocks fill
        // minimum fragment reads: 4 B (hoisted) + 4 A = 8 per wave-dt
        i32x8 bfr[4];
#pragma unroll
        for (int cf = 0; cf < 4; ++cf) {
            const unsigned char* pb = Bs + (cw + cf * 16 + l15) * BK;
            int4 lo = *(const int4*)(pb + o0);
            int4 hi = *(const int4*)(pb + o1);
            bfr[cf] = (i32x8){lo.x, lo.y, lo.z, lo.w, hi.x, hi.y, hi.z, hi.w};
        }
#pragma unroll
        for (int rf = 0; rf < 4; ++rf) {
            const unsigned char* pa = As + (rw + rf * 16 + l15) * BK;
            int4 lo = *(const int4*)(pa + o0);
            int4 hi = *(const int4*)(pa + o1);
            i32x8 a = (i32x8){lo.x, lo.y, lo.z, lo.w, hi.x, hi.y, hi.z, hi.w};
#pragma unroll
            for (int cf = 0; cf < 4; ++cf)
                acc[rf * 4 + cf] = __builtin_amdgcn_mfma_scale_f32_16x16x128_f8f6f4(
                    a, bfr[cf], acc[rf * 4 + cf],
                    0, 0, 0, 0x7F7F7F7F, 0, 0x7F7F7F7F);
        }
        __syncthreads();   // reads done before next stage overwrites
    }

    // epilogue: per-row argmin over this tile's 128 cols -> atomicMin.
    // C/D layout: col = lane&15, row = quad*4 + reg.
    // Packed key: monotone-uint(dist), low 13 bits = global code index.
#pragma unroll
    for (int rf = 0; rf < 4; ++rf) {
#pragma unroll
        for (int r = 0; r < 4; ++r) {
            float bv = 3.4e38f; int bi = 0;
#pragma unroll
            for (int cf = 0; cf < 4; ++cf) {
                int col = cw + cf * 16 + l15;
                float dist = fmaf(-2.0f, acc[rf * 4 + cf][r], es[cf]);
                if (dist < bv) { bv = dist; bi = col; }  // strict <: low col on tie
            }
            unsigned u = __builtin_bit_cast(unsigned, bv);
            u ^= ((unsigned)(((int)u) >> 31)) | 0x80000000u;
            unsigned key = (u & 0xFFFFE000u) | (unsigned)(nbase + bi);
#pragma unroll
            for (int m = 1; m < 16; m <<= 1) {
                unsigned o = __shfl_xor(key, m, 64);
                key = o < key ? o : key;
            }
            if (l15 == 0)
                atomicMin(&candMin[mbase + rw + rf * 16 + quad * 4 + r], key);
        }
    }
}

// ---- kernel 3: gather + ST output + loss atomic ------------------------
// Pure streaming: per row one uniform key read, then 128 float4 slots.
// 2048 blocks (2 row-iters/wave). One plain atomicAdd per block for loss.
__global__ __launch_bounds__(256) void gather_out(
    const float* __restrict__ z, const float* __restrict__ cb,
    const unsigned int* __restrict__ candMin, float* __restrict__ out)
{
    __shared__ float red[4];
    const int tid = threadIdx.x;
    const int w = tid >> 6, lane = tid & 63;
    float lsum = 0.f;
#pragma unroll
    for (int it = 0; it < M_ROWS / (GB_BLOCKS * 4); ++it) {
        int row = (it * GB_BLOCKS + blockIdx.x) * 4 + w;
        int k = (int)(candMin[row] & 8191u);    // uniform per wave
#pragma unroll
        for (int j = 0; j < 2; ++j) {
            int slot = lane + j * 64;
            float4 zv = ((const float4*)(z + (size_t)row * DIM))[slot];
            float4 cv = ((const float4*)(cb + (size_t)k * DIM))[slot];
            float dx = cv.x - zv.x, dy = cv.y - zv.y;
            float dz2 = cv.z - zv.z, dw = cv.w - zv.w;
            float4 o = {zv.x + dx, zv.y + dy, zv.z + dz2, zv.w + dw};  // z + sg(zq-z)
            ((float4*)(out + (size_t)row * DIM))[slot] = o;
            lsum += dx * dx + dy * dy + dz2 * dz2 + dw * dw;
        }
    }
    for (int m = 32; m; m >>= 1) lsum += __shfl_down(lsum, m, 64);
    if (lane == 0) red[w] = lsum;
    __syncthreads();
    if (tid == 0) {
        float t = (red[0] + red[1]) + (red[2] + red[3]);
        atomicAdd(out + OUT0_SIZE, t * (1.1f / (float)OUT0_SIZE));  // vq_loss = 1.1*mean
    }
}

extern "C" void kernel_launch(void* const* d_in, const int* in_sizes, int n_in,
                              void* d_out, int out_size, void* d_ws, size_t ws_size,
                              hipStream_t stream) {
    const float* z = (const float*)d_in[0];     // 16*1024*512
    const float* cb = (const float*)d_in[1];    // 8192*512
    float* out = (float*)d_out;                 // 8388608 + 1
    char* ws = (char*)d_ws;

    // ws layout (bytes)
    unsigned char* z8     = (unsigned char*)(ws);             //  8,388,608
    unsigned char* cb8    = (unsigned char*)(ws + 8388608);   //  4,194,304
    float* enorm          = (float*)(ws + 12582912);          //     32,768
    unsigned int* candMin = (unsigned int*)(ws + 12615680);   //     65,536

    convert_all<<<K_CODES / 4 + M_ROWS * DIM / 2048, 256, 0, stream>>>(
        z, cb, z8, cb8, enorm, candMin, out + OUT0_SIZE);
    gemm_argmin<<<NT * (M_ROWS / BM), 256, 0, stream>>>(z8, cb8, enorm, candMin);
    gather_out<<<GB_BLOCKS, 256, 0, stream>>>(z, cb, candMin, out);
}

// Round 21
// 221.359 us; speedup vs baseline: 1.2070x; 1.0504x over previous
//
#include <hip/hip_runtime.h>

// VQ-VAE quantization: z [16384 x 512] f32, codebook [8192 x 512] f32.
// out = concat(z_st [16384*512] f32, vq_loss [1] f32).
//
// FINAL (R24 = best-measured config, consolidation):
//  - MX-fp8 (e4m3, K=128 scaled MFMA, scale=1.0) scores GEMM; codebook
//    pre-scaled by 2^13 (exact); argmin on d' = 8192||e||^2 - 2 z.(8192e).
//    Argmin flips bounded by 2/8192 per element (== measured absmax).
//  - Packed (dist|idx) u32 keys -> atomicMin into candMin[16384]
//    (deterministic, ties = lowest index by construction).
//  - gemm: 128x128 tile, 4 waves, single-buffer 32KB LDS (4 blocks/CU,
//    VGPR 76), XCD remap (b&7=XCD, 16-block B-tile sharing), XOR-swizzled
//    staging + conflict-free o0/o1 b128 frag reads, es in regs.
//    Best measured: 119.9µs. All structural variants (deep-block,
//    persistent, counted-vmcnt, 512-thr, wider tiles, A-direct) measured
//    and regressed — short K (4 steps) + scaled-MFMA acc in arch VGPRs.
//  - tail: fused converts (+candMin init, loss zero) and pure-streaming
//    gather (uniform key read, one atomicAdd/block). ~100µs floor.
// Session: 294.4 -> 221.8 µs best (this config).

#define M_ROWS 16384
#define K_CODES 8192
#define DIM 512
#define BM 128
#define BN 128
#define BK 128                 // fp8 bytes per K-step (one 16x16x128 MFMA)
#define NT (K_CODES / BN)      // 64 ktiles
#define OUT0_SIZE (M_ROWS * DIM)
#define GB_BLOCKS 1024

typedef int   i32x8 __attribute__((ext_vector_type(8)));
typedef float f32x4 __attribute__((ext_vector_type(4)));

template <bool HI>
__device__ __forceinline__ int pk8(float a, float b, int old) {
    return __builtin_amdgcn_cvt_pk_fp8_f32(a, b, old, HI);
}

__device__ __forceinline__ void gload_lds(const unsigned char* g, unsigned char* l) {
    __builtin_amdgcn_global_load_lds((const __attribute__((address_space(1))) void*)g,
                                     (__attribute__((address_space(3))) void*)l, 16, 0, 0);
}

// ---- kernel 1: fused converts + candMin init ---------------------------
__global__ __launch_bounds__(256) void convert_all(
    const float* __restrict__ z, const float* __restrict__ cb,
    unsigned char* __restrict__ z8, unsigned char* __restrict__ cb8,
    float* __restrict__ enorm, unsigned int* __restrict__ candMin,
    float* __restrict__ lossSlot)
{
    const int tid = threadIdx.x;
    if (blockIdx.x == 0 && tid == 0) *lossSlot = 0.f;   // gather accumulates
    {   // blocks 0..63 init candMin[16384]
        int gi = blockIdx.x * 256 + tid;
        if (gi < M_ROWS) candMin[gi] = 0xFFFFFFFFu;
    }
    if (blockIdx.x < K_CODES / 4) {
        const int w = tid >> 6, lane = tid & 63;
        const int row = blockIdx.x * 4 + w;
        const float* src = cb + (size_t)row * DIM + lane * 8;
        float4 a = *(const float4*)(src);
        float4 b = *(const float4*)(src + 4);
        float ns = a.x * a.x + a.y * a.y + a.z * a.z + a.w * a.w
                 + b.x * b.x + b.y * b.y + b.z * b.z + b.w * b.w;
        const float S = 8192.0f;                 // exact power of 2
        int lo = 0, hi = 0;
        lo = pk8<false>(a.x * S, a.y * S, lo); lo = pk8<true>(a.z * S, a.w * S, lo);
        hi = pk8<false>(b.x * S, b.y * S, hi); hi = pk8<true>(b.z * S, b.w * S, hi);
        *(int2*)(cb8 + (size_t)row * DIM + lane * 8) = make_int2(lo, hi);
        for (int m = 32; m; m >>= 1) ns += __shfl_down(ns, m, 64);
        if (lane == 0) enorm[row] = S * ns;      // 8192 * ||e||^2 (f32-exact norm)
    } else {
        size_t i = ((size_t)(blockIdx.x - K_CODES / 4) * 256 + tid) * 8;
        float4 a = *(const float4*)(z + i);
        float4 b = *(const float4*)(z + i + 4);
        int lo = 0, hi = 0;
        lo = pk8<false>(a.x, a.y, lo); lo = pk8<true>(a.z, a.w, lo);
        hi = pk8<false>(b.x, b.y, hi); hi = pk8<true>(b.z, b.w, hi);
        *(int2*)(z8 + i) = make_int2(lo, hi);
    }
}

// ---- kernel 2: MX-fp8 GEMM (128x128, 4 waves, 4 blocks/CU) + atomicMin -
__global__ __launch_bounds__(256, 2) void gemm_argmin(
    const unsigned char* __restrict__ z8, const unsigned char* __restrict__ cbb,
    const float* __restrict__ enorm, unsigned int* __restrict__ candMin)
{
    __shared__ alignas(32) unsigned char As[BM * BK];   // 16 KB single buffer
    __shared__ alignas(32) unsigned char Bs[BN * BK];   // 16 KB single buffer
    // no Es: LDS = 32768 B exactly

    const int tid = threadIdx.x;
    const int lane = tid & 63;
    const int w = tid >> 6;             // 0..3
    // XCD remap: b&7 = XCD; XCD owns mtiles [xcd*16,xcd*16+16) (1MB A
    // slice, L2-hot); ktile advances every 128 blocks.
    const int b = blockIdx.x;
    const int xcd = b & 7;
    const int idx = b >> 3;             // 0..1023
    const int ktile = idx >> 4;         // 0..63
    const int mtile = xcd * 16 + (idx & 15);
    const int mbase = mtile * BM;
    const int nbase = ktile * BN;

    const int rA = lane >> 3;           // row within 8-row chunk
    const int jG = ((lane & 7) ^ rA) * 16;  // pre-swizzled global 16B chunk
    const int quad = lane >> 4;
    const int l15 = lane & 15;
    const int sw = l15 & 7;
    const int rw = (w >> 1) * 64;       // wave row quadrant
    const int cw = (w & 1) * 64;        // wave col quadrant
    // LDS slot s of row r holds global chunk s^(r&7). Lane needs global
    // chunks 2q,2q+1 -> slots o0=((2q)^sw)*16, o1=o0^16 (lo/hi in exact K
    // order). Full sw: 8 distinct 16B cols per 16 lanes -> bank 4c mod 32,
    // 2 lanes/col = conflict-free.
    const int o0 = ((quad << 1) ^ sw) * 16;
    const int o1 = o0 ^ 16;

    // epilogue norms straight to regs (64B-coalesced per quad, L2-hot)
    float es[4];
#pragma unroll
    for (int cf = 0; cf < 4; ++cf) es[cf] = enorm[nbase + cw + cf * 16 + l15];

    f32x4 acc[16];
#pragma unroll
    for (int i = 0; i < 16; ++i) acc[i] = (f32x4){0.f, 0.f, 0.f, 0.f};

#pragma unroll 1
    for (int dt = 0; dt < 4; ++dt) {
        // stage this K-slab (8 gload_lds / thread)
#pragma unroll
        for (int i_ = 0; i_ < 4; ++i_) {
            int c_ = w * 4 + i_;        // 1KB chunk id (0..15): rows c*8..c*8+7
            int row_ = c_ * 8 + rA;
            int col_ = dt * BK + jG;
            gload_lds(z8 + (size_t)(mbase + row_) * DIM + col_,
                      As + c_ * 1024 + lane * 16);
            gload_lds(cbb + (size_t)(nbase + row_) * DIM + col_,
                      Bs + c_ * 1024 + lane * 16);
        }
        __syncthreads();   // vmcnt(0) drain; other co-resident blocks fill
        // minimum fragment reads: 4 B (hoisted) + 4 A = 8 per wave-dt
        i32x8 bfr[4];
#pragma unroll
        for (int cf = 0; cf < 4; ++cf) {
            const unsigned char* pb = Bs + (cw + cf * 16 + l15) * BK;
            int4 lo = *(const int4*)(pb + o0);
            int4 hi = *(const int4*)(pb + o1);
            bfr[cf] = (i32x8){lo.x, lo.y, lo.z, lo.w, hi.x, hi.y, hi.z, hi.w};
        }
#pragma unroll
        for (int rf = 0; rf < 4; ++rf) {
            const unsigned char* pa = As + (rw + rf * 16 + l15) * BK;
            int4 lo = *(const int4*)(pa + o0);
            int4 hi = *(const int4*)(pa + o1);
            i32x8 a = (i32x8){lo.x, lo.y, lo.z, lo.w, hi.x, hi.y, hi.z, hi.w};
#pragma unroll
            for (int cf = 0; cf < 4; ++cf)
                acc[rf * 4 + cf] = __builtin_amdgcn_mfma_scale_f32_16x16x128_f8f6f4(
                    a, bfr[cf], acc[rf * 4 + cf],
                    0, 0, 0, 0x7F7F7F7F, 0, 0x7F7F7F7F);
        }
        __syncthreads();   // reads done before next stage overwrites
    }

    // epilogue: per-row argmin over this tile's 128 cols -> atomicMin.
    // C/D layout: col = lane&15, row = quad*4 + reg.
    // Packed key: monotone-uint(dist), low 13 bits = global code index.
#pragma unroll
    for (int rf = 0; rf < 4; ++rf) {
#pragma unroll
        for (int r = 0; r < 4; ++r) {
            float bv = 3.4e38f; int bi = 0;
#pragma unroll
            for (int cf = 0; cf < 4; ++cf) {
                int col = cw + cf * 16 + l15;
                float dist = fmaf(-2.0f, acc[rf * 4 + cf][r], es[cf]);
                if (dist < bv) { bv = dist; bi = col; }  // strict <: low col on tie
            }
            unsigned u = __builtin_bit_cast(unsigned, bv);
            u ^= ((unsigned)(((int)u) >> 31)) | 0x80000000u;
            unsigned key = (u & 0xFFFFE000u) | (unsigned)(nbase + bi);
#pragma unroll
            for (int m = 1; m < 16; m <<= 1) {
                unsigned o = __shfl_xor(key, m, 64);
                key = o < key ? o : key;
            }
            if (l15 == 0)
                atomicMin(&candMin[mbase + rw + rf * 16 + quad * 4 + r], key);
        }
    }
}

// ---- kernel 3: gather + ST output + loss atomic ------------------------
// Pure streaming: per row one uniform key read, then 128 float4 slots.
// One plain atomicAdd per block for the loss.
__global__ __launch_bounds__(256) void gather_out(
    const float* __restrict__ z, const float* __restrict__ cb,
    const unsigned int* __restrict__ candMin, float* __restrict__ out)
{
    __shared__ float red[4];
    const int tid = threadIdx.x;
    const int w = tid >> 6, lane = tid & 63;
    float lsum = 0.f;
#pragma unroll
    for (int it = 0; it < M_ROWS / (GB_BLOCKS * 4); ++it) {
        int row = (it * GB_BLOCKS + blockIdx.x) * 4 + w;
        int k = (int)(candMin[row] & 8191u);    // uniform per wave
#pragma unroll
        for (int j = 0; j < 2; ++j) {
            int slot = lane + j * 64;
            float4 zv = ((const float4*)(z + (size_t)row * DIM))[slot];
            float4 cv = ((const float4*)(cb + (size_t)k * DIM))[slot];
            float dx = cv.x - zv.x, dy = cv.y - zv.y;
            float dz2 = cv.z - zv.z, dw = cv.w - zv.w;
            float4 o = {zv.x + dx, zv.y + dy, zv.z + dz2, zv.w + dw};  // z + sg(zq-z)
            ((float4*)(out + (size_t)row * DIM))[slot] = o;
            lsum += dx * dx + dy * dy + dz2 * dz2 + dw * dw;
        }
    }
    for (int m = 32; m; m >>= 1) lsum += __shfl_down(lsum, m, 64);
    if (lane == 0) red[w] = lsum;
    __syncthreads();
    if (tid == 0) {
        float t = (red[0] + red[1]) + (red[2] + red[3]);
        atomicAdd(out + OUT0_SIZE, t * (1.1f / (float)OUT0_SIZE));  // vq_loss = 1.1*mean
    }
}

extern "C" void kernel_launch(void* const* d_in, const int* in_sizes, int n_in,
                              void* d_out, int out_size, void* d_ws, size_t ws_size,
                              hipStream_t stream) {
    const float* z = (const float*)d_in[0];     // 16*1024*512
    const float* cb = (const float*)d_in[1];    // 8192*512
    float* out = (float*)d_out;                 // 8388608 + 1
    char* ws = (char*)d_ws;

    // ws layout (bytes)
    unsigned char* z8     = (unsigned char*)(ws);             //  8,388,608
    unsigned char* cb8    = (unsigned char*)(ws + 8388608);   //  4,194,304
    float* enorm          = (float*)(ws + 12582912);          //     32,768
    unsigned int* candMin = (unsigned int*)(ws + 12615680);   //     65,536

    convert_all<<<K_CODES / 4 + M_ROWS * DIM / 2048, 256, 0, stream>>>(
        z, cb, z8, cb8, enorm, candMin, out + OUT0_SIZE);
    gemm_argmin<<<NT * (M_ROWS / BM), 256, 0, stream>>>(z8, cb8, enorm, candMin);
    gather_out<<<GB_BLOCKS, 256, 0, stream>>>(z, cb, candMin, out);
}